// Round 11
// baseline (120.850 us; speedup 1.0000x reference)
//
#include <hip/hip_runtime.h>
#include <math.h>

#define Bn 8
#define Hn 256
#define Wn 256
#define HW (Hn * Wn)
#define ROWS 4
#define RP 264  // padded row length (words); data at [4..259], zeros at 3/260
#define ZW (12 * RP)  // zero region: rowsF[ZW .. ZW+63] == 0

typedef __attribute__((ext_vector_type(8))) short bf16x8;
typedef __attribute__((ext_vector_type(4))) float f32x4;

// Pack two fp32 (raw bits) into packed bf16x2 by truncation: one v_perm.
__device__ __forceinline__ unsigned int pk_bits(unsigned int lo,
                                                unsigned int hi) {
  return __builtin_amdgcn_perm(hi, lo, 0x07060302u);
}
__device__ __forceinline__ unsigned int pk_bf16(float lo, float hi) {
  return pk_bits(__float_as_uint(lo), __float_as_uint(hi));
}

// k-slot -> tap mapping (tap = pl*9 + rr*3 + dx), chosen so that on every
// gather instruction q0 and q1 hit DISJOINT 16-bank halves:
//   pairs (pl,rr=0,dx)<->(pl,rr=2,dx): addr delta 2*RP=528 == 16 (mod 32)
//   pairs (pl0,rr=1,dx)<->(pl1,rr=1,dx): delta 6*RP=1584 == 16 (mod 32)
// (RP=264: 264*2=528=16*33 -> 528 mod 32 = 16; 6*264=1584 mod 32 = 16.)
// q0 slots jh=0..7 take pair-firsts, q1 the pair-seconds, q2 jh=0,1 the
// leftover 9th pair; q2 jh>=2 and all q3 read the zero region (broadcast).
__device__ __constant__ const int T0c[8] = {0, 1, 2, 9, 10, 11, 3, 4};
__device__ __constant__ const int T1c[8] = {6, 7, 8, 15, 16, 17, 12, 13};
__device__ __constant__ const int T2c[8] = {5, 14, -1, -1, -1, -1, -1, -1};

// Kernel A (R11): fused conv1(2->64,3x3)+ReLU -> conv2(64->1) -> sigmoid ->
// gate, conv1 on bf16 MFMA, direct LDS gather (no im2col buffer).
//
// R10 diagnosis: no pipe saturated (VALU ~35% true, MFMA 11%, HBM 7%,
// conflicts ~0) but occupancy only ~29% -> the serial per-strip chains
// (MFMA -> fmaf chain -> 2 shfl -> exp -> rcp) are not overlapped by enough
// concurrent waves. R11: ROWS 8->4 doubles the grid to 3072 blocks
// (12/CU nominal; LDS 17 KB no longer caps residency) and the conv2 chain
// is split into two parallel 8-term chains (serial depth ~halved).
__global__ __launch_bounds__(256) void sim_kernel(
    const float* __restrict__ x,   // (8,7,256,256)
    const float* __restrict__ W1,  // (6,64,2,3,3)
    const float* __restrict__ b1,  // (6,64)
    const float* __restrict__ W2,  // (6,1,64,1,1)
    const float* __restrict__ b2,  // (6,1)
    float* __restrict__ comb)      // (8,7,256,256)
{
  __shared__ float rowsF[12 * RP + 64];  // 12.9 KB rows + zero region
  __shared__ uint4 wq[4][64];            // 4 KB A-frags

  int bi = blockIdx.x;
  int n  = bi >> 9;            // 0..5
  int b  = (bi >> 6) & 7;      // 0..7
  int h0 = (bi & 63) * ROWS;   // chunk start row
  int cc = (n < 3) ? n : n + 1;
  int t = threadIdx.x;

  const float* xb     = x + (size_t)b * 7 * HW;
  const float* basep  = xb + 3 * HW;
  const float* checkp = xb + (size_t)cc * HW;

  // ---- stage weights in MFMA A-layout with the k-remap ----
  {
    int f = t >> 6, qq = (t >> 4) & 3, m = t & 15;
    int bsrc = (n < 3) ? 0 : 1;  // weight input-ch that multiplies BASE
    const float* wch = W1 + ((size_t)(n * 64 + 16 * f + m)) * 18;
    unsigned int kv[4];
#pragma unroll
    for (int jj = 0; jj < 4; ++jj) {
      int ja = 2 * jj, jb = 2 * jj + 1;
      int ta = (qq == 0) ? T0c[ja] : (qq == 1) ? T1c[ja]
               : (qq == 2) ? T2c[ja] : -1;
      int tb = (qq == 0) ? T0c[jb] : (qq == 1) ? T1c[jb]
               : (qq == 2) ? T2c[jb] : -1;
      float va = 0.f, vb = 0.f;
      if (ta >= 0) {
        int pl = ta / 9, rem = ta - pl * 9;
        va = wch[(pl ? 1 - bsrc : bsrc) * 9 + rem];
      }
      if (tb >= 0) {
        int pl = tb / 9, rem = tb - pl * 9;
        vb = wch[(pl ? 1 - bsrc : bsrc) * 9 + rem];
      }
      kv[jj] = pk_bf16(va, vb);
    }
    wq[f][(qq << 4) + m] = make_uint4(kv[0], kv[1], kv[2], kv[3]);
  }

  // ---- per-lane conv2/bias params (global loads, no LDS dep) ----
  int lane = t & 63, wvid = t >> 6;
  int q = lane >> 4, m_ = lane & 15;
  float w2v[4][4];
  f32x4 b1vv[4];
#pragma unroll
  for (int f = 0; f < 4; ++f) {
    float4 tw = *(const float4*)&W2[n * 64 + 16 * f + 4 * q];
    float4 tb = *(const float4*)&b1[n * 64 + 16 * f + 4 * q];
    w2v[f][0] = tw.x; w2v[f][1] = tw.y; w2v[f][2] = tw.z; w2v[f][3] = tw.w;
    b1vv[f][0] = tb.x; b1vv[f][1] = tb.y;
    b1vv[f][2] = tb.z; b1vv[f][3] = tb.w;
  }
  float bb = b2[n];

  // ---- stage raw rows: 12 rows (2 planes x 6) -> rowsF[rf*RP + 4 + col] --
  {
    int col = (t & 63) << 2;
#pragma unroll
    for (int it = 0; it < 3; ++it) {
      int rf = it * 4 + (t >> 6);  // 0..11 = pl*6 + j
      int pl = (rf >= 6) ? 1 : 0;
      int j  = rf - pl * 6;
      int hh = h0 - 1 + j;
      const float* src = pl ? checkp : basep;
      float4 val = make_float4(0.f, 0.f, 0.f, 0.f);
      if ((unsigned)hh < (unsigned)Hn)
        val = *(const float4*)(src + hh * Wn + col);
      *(float4*)&rowsF[rf * RP + 4 + col] = val;
    }
    if (t < 12) {  // edge zeros
      rowsF[t * RP + 3] = 0.f;
      rowsF[t * RP + 260] = 0.f;
    }
    if (t >= 192) rowsF[ZW + (t - 192)] = 0.f;  // zero region (64 words)
  }

  // ---- per-lane gather table: slot jh (k = 8q + jh) ----
  const unsigned int* rowsU = (const unsigned int*)rowsF;
  unsigned int addr[8], vbit[8];
#pragma unroll
  for (int jh = 0; jh < 8; ++jh) {
    int tap = (q == 0) ? T0c[jh] : (q == 1) ? T1c[jh]
              : (q == 2) ? T2c[jh] : -1;
    if (tap >= 0) {
      int pl = tap / 9, rem = tap - pl * 9;
      int rr = rem / 3, dx = rem - rr * 3;
      addr[jh] = (pl * 6 + rr) * RP + 3 + dx + wvid * 64 + m_;
      vbit[jh] = 1u;
    } else {
      addr[jh] = (unsigned)ZW;  // zero region; +16/32/48 also zero
      vbit[jh] = 0u;
    }
  }

  __syncthreads();

  // A fragments (contiguous 16 B per lane, conflict-free)
  bf16x8 afrag[4];
#pragma unroll
  for (int f = 0; f < 4; ++f) afrag[f] = *(const bf16x8*)&wq[f][lane];

  float* combcc = comb + ((size_t)b * 7 + cc) * HW;
  float* comb3  = comb + ((size_t)b * 7 + 3) * HW;
  int pxs = wvid * 64 + lane;

#pragma unroll 1
  for (int r = 0; r < ROWS; ++r) {
    int h = h0 + r;
    unsigned int rowoff = (unsigned)(r * RP);

    unsigned int base[8];
#pragma unroll
    for (int jh = 0; jh < 8; ++jh) base[jh] = addr[jh] + vbit[jh] * rowoff;

    float g[4];
#pragma unroll
    for (int half = 0; half < 2; ++half) {
      // gather strip pair (2*half, 2*half+1): one vaddr, imm offsets
      // {32*half, 32*half+16} words -> ds_read2_b32
      unsigned int dlo[8], dhi[8];
#pragma unroll
      for (int jh = 0; jh < 8; ++jh) {
        dlo[jh] = rowsU[base[jh] + half * 32];
        dhi[jh] = rowsU[base[jh] + half * 32 + 16];
      }
#pragma unroll
      for (int j = 0; j < 2; ++j) {
        const unsigned int* d = j ? dhi : dlo;
        union { unsigned int u[4]; bf16x8 v; } bu;
#pragma unroll
        for (int jj = 0; jj < 4; ++jj)
          bu.u[jj] = pk_bits(d[2 * jj], d[2 * jj + 1]);

        f32x4 acc[4];
#pragma unroll
        for (int f = 0; f < 4; ++f)
          acc[f] = __builtin_amdgcn_mfma_f32_16x16x32_bf16(afrag[f], bu.v,
                                                           b1vv[f], 0, 0, 0);

        // conv2: two parallel 8-term chains (halved serial depth)
        float spA = 0.f, spB = 0.f;
#pragma unroll
        for (int rr = 0; rr < 4; ++rr) {
          spA = fmaf(w2v[0][rr], fmaxf(acc[0][rr], 0.f), spA);
          spB = fmaf(w2v[2][rr], fmaxf(acc[2][rr], 0.f), spB);
          spA = fmaf(w2v[1][rr], fmaxf(acc[1][rr], 0.f), spA);
          spB = fmaf(w2v[3][rr], fmaxf(acc[3][rr], 0.f), spB);
        }
        float sp = spA + spB;
        sp += __shfl_xor(sp, 16, 64);
        sp += __shfl_xor(sp, 32, 64);
        sp += bb;

        float e = __builtin_amdgcn_exp2f(sp * -1.442695041f);
        g[2 * half + j] = __builtin_amdgcn_rcpf(1.f + e);
      }
    }

    // Coalesced store: lane l -> px = wvid*64 + l, gate g[l>>4]
    int hi = lane >> 4;
    float gsel = (hi == 0) ? g[0] : (hi == 1) ? g[1] : (hi == 2) ? g[2] : g[3];
    float ccv = rowsF[(6 + r + 1) * RP + 4 + pxs];  // check center
    combcc[h * Wn + pxs] = gsel * ccv;
    if (n == 0) comb3[h * Wn + pxs] = rowsF[(r + 1) * RP + 4 + pxs];
  }
}

// Kernel B: final mixing conv (7->7, 3x3, SAME), LDS-staged.
// Block = (b, 2-row chunk) -> 1024 blocks (4 blocks/CU, 16 waves/CU).
// LDS = 7 planes x 4 rows x RP = 29.6 KB. Thread = (row, 2 px).
__global__ __launch_bounds__(256) void mix_kernel(
    const float* __restrict__ comb,  // (8,7,256,256)
    const float* __restrict__ Wm,    // (7,7,3,3)
    const float* __restrict__ bm,    // (7,)
    float* __restrict__ out)         // (8,7,256,256)
{
  __shared__ float mr[28 * RP];  // 29.6 KB

  int bi = blockIdx.x;           // 0..1023
  int b  = bi >> 7;
  int h0 = (bi & 127) << 1;
  int t = threadIdx.x;

  // stage: 28 rows (ic*4 + j) x 64 float4
  for (int u = t; u < 28 * 64; u += 256) {
    int rf = u >> 6;             // 0..27 = ic*4 + j
    int col = (u & 63) << 2;
    int ic = rf >> 2, j = rf & 3;
    int hh = h0 - 1 + j;
    float4 v = make_float4(0.f, 0.f, 0.f, 0.f);
    if ((unsigned)hh < (unsigned)Hn)
      v = *(const float4*)(comb + ((size_t)b * 7 + ic) * HW + hh * Wn + col);
    *(float4*)&mr[rf * RP + 4 + col] = v;
  }
  if (t < 28) {
    mr[t * RP + 3] = 0.f;
    mr[t * RP + 260] = 0.f;
  }
  __syncthreads();

  int r   = t >> 7;           // local row 0..1
  int px0 = (t & 127) << 1;   // 0..254
  int h   = h0 + r;

  float acc[7][2];
#pragma unroll
  for (int oc = 0; oc < 7; ++oc) {
    float bv = bm[oc];
    acc[oc][0] = bv;
    acc[oc][1] = bv;
  }

#pragma unroll 1
  for (int ic = 0; ic < 7; ++ic) {
    float w[3][4];
#pragma unroll
    for (int dy = 0; dy < 3; ++dy) {
      const float* rp = &mr[(ic * 4 + r + dy) * RP + 3 + px0];
      w[dy][0] = rp[0]; w[dy][1] = rp[1];  // adjacent -> ds_read2
      w[dy][2] = rp[2]; w[dy][3] = rp[3];
    }
    const float* wp = Wm + ic * 9;
#pragma unroll
    for (int oc = 0; oc < 7; ++oc) {
      const float* wo = wp + oc * 63;
#pragma unroll
      for (int dy = 0; dy < 3; ++dy)
#pragma unroll
        for (int dx = 0; dx < 3; ++dx) {
          float wvv = wo[dy * 3 + dx];
          acc[oc][0] = fmaf(wvv, w[dy][0 + dx], acc[oc][0]);
          acc[oc][1] = fmaf(wvv, w[dy][1 + dx], acc[oc][1]);
        }
    }
  }

  float* ob = out + (size_t)b * 7 * HW + h * Wn + px0;
#pragma unroll
  for (int oc = 0; oc < 7; ++oc)
    *(float2*)(ob + (size_t)oc * HW) = make_float2(acc[oc][0], acc[oc][1]);
}

extern "C" void kernel_launch(void* const* d_in, const int* in_sizes, int n_in,
                              void* d_out, int out_size, void* d_ws, size_t ws_size,
                              hipStream_t stream) {
  const float* x  = (const float*)d_in[0];
  const float* W1 = (const float*)d_in[1];
  const float* b1 = (const float*)d_in[2];
  const float* W2 = (const float*)d_in[3];
  const float* b2 = (const float*)d_in[4];
  const float* Wm = (const float*)d_in[5];
  const float* bm = (const float*)d_in[6];
  float* out  = (float*)d_out;
  float* comb = (float*)d_ws;  // 8*7*256*256 floats = 14.7 MB

  sim_kernel<<<6 * 8 * (Hn / ROWS), 256, 0, stream>>>(x, W1, b1, W2, b2, comb);
  mix_kernel<<<8 * (Hn / 2), 256, 0, stream>>>(comb, Wm, bm, out);
}